// Round 3
// baseline (46.815 us; speedup 1.0000x reference)
//
#include <hip/hip_runtime.h>
#include <math.h>

#define LN2_INV  1.4426950408889634f   // 1/ln(2)
#define INV_2PI  0.15915494309189535f  // 1/(2*pi)

// out[h,l] = 2 * Re( sum_n Ccoef[h,n] * exp(dtA[h,n] * l) )
//   dt    = exp(log_dt[h])
//   A     = -exp(log_A_real) + i*A_imag
//   dtA   = A*dt
//   Ccoef = (C0 + i*C1) * (exp(dtA)-1)/A
//
// Each block handles one h and lPerBlock=1024 contiguous l values
// (256 threads x 4 l/thread, float4 store). Per-h coefficients are
// computed by the first Nh lanes into LDS (no workspace needed).
__global__ __launch_bounds__(256) void s4d_main(
    const float* __restrict__ log_dt,
    const float* __restrict__ C,
    const float* __restrict__ log_A_real,
    const float* __restrict__ A_imag,
    float* __restrict__ out,
    int Nh, int L, int blocksPerH, int lPerBlock)
{
    extern __shared__ float smem[];
    float* s_ar = smem;            // dtA_r * (1/ln2)   (for exp2)
    float* s_ai = smem + Nh;       // dtA_i * (1/2pi)   (revolutions/step)
    float* s_cr = smem + 2 * Nh;   // 2*Ccoef_r
    float* s_ci = smem + 3 * Nh;   // 2*Ccoef_i

    const int bid = blockIdx.x;
    const int h   = bid / blocksPerH;
    const int lb  = bid - h * blocksPerH;
    const int tid = threadIdx.x;

    // ---- per-h coefficient setup (accurate libm versions; 32 lanes only) ----
    for (int n = tid; n < Nh; n += blockDim.x) {
        const float dt = expf(log_dt[h]);
        const float Ar = -expf(log_A_real[h * Nh + n]);
        const float Ai = A_imag[h * Nh + n];
        const float xr = Ar * dt;          // Re(dtA)
        const float xi = Ai * dt;          // Im(dtA)
        // E - 1 = exp(dtA) - 1
        const float em = expf(xr);
        const float cs = cosf(xi);
        const float sn = sinf(xi);
        const float er = fmaf(em, cs, -1.0f);
        const float ei = em * sn;
        // t = (E-1)/A = (E-1)*conj(A)/|A|^2
        const float inv = 1.0f / fmaf(Ar, Ar, Ai * Ai);
        const float tr = fmaf(er, Ar,  ei * Ai) * inv;
        const float ti = fmaf(ei, Ar, -er * Ai) * inv;
        // coef = Cc * t, with the final *2 folded in
        const float c0 = C[(h * Nh + n) * 2 + 0];
        const float c1 = C[(h * Nh + n) * 2 + 1];
        s_cr[n] = 2.0f * fmaf(c0, tr, -c1 * ti);
        s_ci[n] = 2.0f * fmaf(c0, ti,  c1 * tr);
        s_ar[n] = xr * LN2_INV;
        s_ai[n] = xi * INV_2PI;
    }
    __syncthreads();

    // ---- main evaluation: 4 l-values per thread ----
    const int l0 = lb * lPerBlock + tid * 4;
    if (l0 >= L) return;
    const float lf0 = (float)l0;

    float acc[4] = {0.0f, 0.0f, 0.0f, 0.0f};

    for (int n = 0; n < Nh; ++n) {
        const float ar = s_ar[n];
        const float ai = s_ai[n];
        const float cr = s_cr[n];
        const float ci = s_ci[n];
#pragma unroll
        for (int j = 0; j < 4; ++j) {
            const float lf = lf0 + (float)j;
            const float e  = __builtin_amdgcn_exp2f(ar * lf);          // |K|
            const float th = __builtin_amdgcn_fractf(ai * lf);         // phase in revs, [0,1)
            const float s  = __builtin_amdgcn_sinf(th);                // sin(2*pi*th)
            const float c  = __builtin_amdgcn_cosf(th);                // cos(2*pi*th)
            // Re(coef * K) = cr*kr - ci*ki, kr = e*c, ki = e*s
            acc[j] = fmaf(e, fmaf(cr, c, -ci * s), acc[j]);
        }
    }

    const size_t base = (size_t)h * (size_t)L + (size_t)l0;
    if (l0 + 3 < L) {
        float4 v = make_float4(acc[0], acc[1], acc[2], acc[3]);
        *reinterpret_cast<float4*>(&out[base]) = v;
    } else {
        out[base] = acc[0];
        if (l0 + 1 < L) out[base + 1] = acc[1];
        if (l0 + 2 < L) out[base + 2] = acc[2];
    }
}

extern "C" void kernel_launch(void* const* d_in, const int* in_sizes, int n_in,
                              void* d_out, int out_size, void* d_ws, size_t ws_size,
                              hipStream_t stream)
{
    const float* log_dt     = (const float*)d_in[0];
    const float* C          = (const float*)d_in[1];
    const float* log_A_real = (const float*)d_in[2];
    const float* A_imag     = (const float*)d_in[3];
    float* out = (float*)d_out;

    const int H  = in_sizes[0];               // log_dt is (H,)
    const int Nh = in_sizes[2] / H;           // log_A_real is (H, Nh)
    const int L  = out_size / H;              // out is (H, L)

    const int lPerBlock  = 256 * 4;
    const int blocksPerH = (L + lPerBlock - 1) / lPerBlock;
    const int grid       = H * blocksPerH;
    const size_t smem    = 4 * (size_t)Nh * sizeof(float);

    hipLaunchKernelGGL(s4d_main, dim3(grid), dim3(256), smem, stream,
                       log_dt, C, log_A_real, A_imag, out,
                       Nh, L, blocksPerH, lPerBlock);
}

// Round 4
// 21.763 us; speedup vs baseline: 2.1511x; 2.1511x over previous
//
#include <hip/hip_runtime.h>
#include <math.h>

#define LN2_INV  1.4426950408889634f   // 1/ln(2)
#define INV_2PI  0.15915494309189535f  // 1/(2*pi)

// out[h,l] = 2 * Re( sum_n coef[h,n] * S[h,n]^l ),  S = exp(dtA)
//
// Per thread: T=16 contiguous l values. Transcendental eval only at l0
// (y0 = Re(P), y1 = Re(P*S), P = 2*coef*S^l0), then Goertzel recurrence
//   y(l+1) = 2*Re(S)*y(l) - |S|^2*y(l-1)
// generates the rest at 3 full-rate VALU ops per (n,l).
//
// Block = one head's 4096-l chunk (256 threads x 16). Per-(h,n) constants
// in LDS as two float4s -> broadcast ds_read_b128 (conflict-free).
#define T_PER_THREAD 16

__global__ __launch_bounds__(256) void s4d_goertzel(
    const float* __restrict__ log_dt,
    const float* __restrict__ C,
    const float* __restrict__ log_A_real,
    const float* __restrict__ A_imag,
    float* __restrict__ out,
    int Nh, int L, int blocksPerH)
{
    extern __shared__ float4 smem4[];
    float4* sA = smem4;          // {ar=dtA_r/ln2, ai=dtA_i/2pi, cr=2*coef_r, ci=2*coef_i}
    float4* sB = smem4 + Nh;     // {sr=Re(S), si=Im(S), a2=2*sr, nb=|S|^2}

    const int bid = blockIdx.x;
    const int h   = bid / blocksPerH;
    const int lb  = bid - h * blocksPerH;
    const int tid = threadIdx.x;

    // ---- per-(h,n) setup: first Nh lanes, accurate libm ----
    for (int n = tid; n < Nh; n += blockDim.x) {
        const float dt = expf(log_dt[h]);
        const float Ar = -expf(log_A_real[h * Nh + n]);
        const float Ai = A_imag[h * Nh + n];
        const float xr = Ar * dt;            // Re(dtA)
        const float xi = Ai * dt;            // Im(dtA)
        const float em = expf(xr);
        const float cs = cosf(xi);
        const float sn = sinf(xi);
        const float sr = em * cs;            // Re(S)
        const float si = em * sn;            // Im(S)
        // (E-1)/A = (S-1)*conj(A)/|A|^2
        const float er = sr - 1.0f;
        const float ei = si;
        const float inv = 1.0f / fmaf(Ar, Ar, Ai * Ai);
        const float tr = fmaf(er, Ar,  ei * Ai) * inv;
        const float ti = fmaf(ei, Ar, -er * Ai) * inv;
        const float c0 = C[(h * Nh + n) * 2 + 0];
        const float c1 = C[(h * Nh + n) * 2 + 1];
        const float cr = 2.0f * fmaf(c0, tr, -c1 * ti);   // 2*coef_r
        const float ci = 2.0f * fmaf(c0, ti,  c1 * tr);   // 2*coef_i
        sA[n] = make_float4(xr * LN2_INV, xi * INV_2PI, cr, ci);
        sB[n] = make_float4(sr, si, sr + sr, fmaf(sr, sr, si * si));
    }
    __syncthreads();

    const int l0 = lb * (256 * T_PER_THREAD) + tid * T_PER_THREAD;
    if (l0 >= L) return;
    const float lf0 = (float)l0;

    float acc[T_PER_THREAD];
#pragma unroll
    for (int j = 0; j < T_PER_THREAD; ++j) acc[j] = 0.0f;

    for (int n = 0; n < Nh; ++n) {
        const float4 qa = sA[n];   // ar, ai, cr, ci
        const float4 qb = sB[n];   // sr, si, a2, nb
        // P = 2*coef * S^l0  (the only transcendentals)
        const float e  = __builtin_amdgcn_exp2f(qa.x * lf0);
        const float th = __builtin_amdgcn_fractf(qa.y * lf0);
        const float s  = __builtin_amdgcn_sinf(th);     // sin(2*pi*th)
        const float c  = __builtin_amdgcn_cosf(th);     // cos(2*pi*th)
        const float kr = e * c;
        const float ki = e * s;
        const float Pr = fmaf(qa.z, kr, -qa.w * ki);
        const float Pi = fmaf(qa.z, ki,  qa.w * kr);
        // y(l0), y(l0+1) = Re(P), Re(P*S)
        float y0 = Pr;
        float y1 = fmaf(Pr, qb.x, -Pi * qb.y);
        acc[0] += y0;
        acc[1] += y1;
#pragma unroll
        for (int j = 2; j < T_PER_THREAD; ++j) {
            const float t = qb.w * y0;            // |S|^2 * y(l-1)
            const float y = fmaf(qb.z, y1, -t);   // 2Re(S)*y(l) - t
            acc[j] += y;
            y0 = y1;
            y1 = y;
        }
    }

    const size_t base = (size_t)h * (size_t)L + (size_t)l0;
    if (l0 + T_PER_THREAD <= L) {
#pragma unroll
        for (int k = 0; k < T_PER_THREAD / 4; ++k) {
            *reinterpret_cast<float4*>(&out[base + 4 * k]) =
                make_float4(acc[4 * k], acc[4 * k + 1], acc[4 * k + 2], acc[4 * k + 3]);
        }
    } else {
        for (int j = 0; j < T_PER_THREAD && l0 + j < L; ++j) out[base + j] = acc[j];
    }
}

extern "C" void kernel_launch(void* const* d_in, const int* in_sizes, int n_in,
                              void* d_out, int out_size, void* d_ws, size_t ws_size,
                              hipStream_t stream)
{
    const float* log_dt     = (const float*)d_in[0];
    const float* C          = (const float*)d_in[1];
    const float* log_A_real = (const float*)d_in[2];
    const float* A_imag     = (const float*)d_in[3];
    float* out = (float*)d_out;

    const int H  = in_sizes[0];               // log_dt is (H,)
    const int Nh = in_sizes[2] / H;           // log_A_real is (H, Nh)
    const int L  = out_size / H;              // out is (H, L)

    const int lPerBlock  = 256 * T_PER_THREAD;            // 4096
    const int blocksPerH = (L + lPerBlock - 1) / lPerBlock;
    const int grid       = H * blocksPerH;
    const size_t smem    = 2 * (size_t)Nh * sizeof(float4);

    hipLaunchKernelGGL(s4d_goertzel, dim3(grid), dim3(256), smem, stream,
                       log_dt, C, log_A_real, A_imag, out,
                       Nh, L, blocksPerH);
}

// Round 5
// 19.974 us; speedup vs baseline: 2.3438x; 1.0896x over previous
//
#include <hip/hip_runtime.h>
#include <math.h>

#define LN2_INV  1.4426950408889634f   // 1/ln(2)
#define INV_2PI  0.15915494309189535f  // 1/(2*pi)

typedef float v2f __attribute__((ext_vector_type(2)));

// out[h,l] = 2 * Re( sum_n coef[h,n] * S[h,n]^l ),  S = exp(dtA)
//
// Goertzel: transcendentals only at l0 per (n,thread); then
//   y(l+1) = 2Re(S)*y(l) - |S|^2*y(l-1)
// n processed in PAIRS as float2 (v_pk_fma_f32 path + 2 independent
// chains for latency hiding). LDS constants software-pipelined one
// pair ahead to hide ds_read latency. Requires Nh even (here Nh=32).
#define T_PER_THREAD 16

__global__ __launch_bounds__(256) void s4d_goertzel2(
    const float* __restrict__ log_dt,
    const float* __restrict__ C,
    const float* __restrict__ log_A_real,
    const float* __restrict__ A_imag,
    float* __restrict__ out,
    int Nh, int L, int blocksPerH)
{
    extern __shared__ float4 smem4[];
    float4* sA = smem4;          // {dtA_r/ln2, dtA_i/2pi, 2*coef_r, 2*coef_i}
    float4* sB = smem4 + Nh;     // {Re(S), Im(S), 2*Re(S), |S|^2}

    const int bid = blockIdx.x;
    const int h   = bid / blocksPerH;
    const int lb  = bid - h * blocksPerH;
    const int tid = threadIdx.x;

    // ---- per-(h,n) setup: first Nh lanes, accurate libm ----
    for (int n = tid; n < Nh; n += blockDim.x) {
        const float dt = expf(log_dt[h]);
        const float Ar = -expf(log_A_real[h * Nh + n]);
        const float Ai = A_imag[h * Nh + n];
        const float xr = Ar * dt;            // Re(dtA)
        const float xi = Ai * dt;            // Im(dtA)
        const float em = expf(xr);
        const float cs = cosf(xi);
        const float sn = sinf(xi);
        const float sr = em * cs;            // Re(S)
        const float si = em * sn;            // Im(S)
        const float er = sr - 1.0f;          // (S-1)
        const float ei = si;
        const float inv = 1.0f / fmaf(Ar, Ar, Ai * Ai);
        const float tr = fmaf(er, Ar,  ei * Ai) * inv;   // (S-1)/A
        const float ti = fmaf(ei, Ar, -er * Ai) * inv;
        const float c0 = C[(h * Nh + n) * 2 + 0];
        const float c1 = C[(h * Nh + n) * 2 + 1];
        const float cr = 2.0f * fmaf(c0, tr, -c1 * ti);  // 2*coef_r
        const float ci = 2.0f * fmaf(c0, ti,  c1 * tr);  // 2*coef_i
        sA[n] = make_float4(xr * LN2_INV, xi * INV_2PI, cr, ci);
        sB[n] = make_float4(sr, si, sr + sr, fmaf(sr, sr, si * si));
    }
    __syncthreads();

    const int l0 = lb * (256 * T_PER_THREAD) + tid * T_PER_THREAD;
    if (l0 >= L) return;
    const float lf0 = (float)l0;

    v2f acc2[T_PER_THREAD];
#pragma unroll
    for (int j = 0; j < T_PER_THREAD; ++j) acc2[j] = (v2f){0.0f, 0.0f};

    // software-pipelined pair loop over n
    float4 qa0 = sA[0], qb0 = sB[0], qa1 = sA[1], qb1 = sB[1];
    for (int n = 0; n < Nh; n += 2) {
        const int np = (n + 2 < Nh) ? (n + 2) : 0;   // prefetch (wraps harmlessly)
        const float4 ra0 = sA[np],     rb0 = sB[np];
        const float4 ra1 = sA[np + 1], rb1 = sB[np + 1];

        // --- scalar transcendental init for the two chains ---
        const float e0  = __builtin_amdgcn_exp2f(qa0.x * lf0);
        const float th0 = __builtin_amdgcn_fractf(qa0.y * lf0);
        const float s0  = __builtin_amdgcn_sinf(th0);
        const float c0  = __builtin_amdgcn_cosf(th0);
        const float e1  = __builtin_amdgcn_exp2f(qa1.x * lf0);
        const float th1 = __builtin_amdgcn_fractf(qa1.y * lf0);
        const float s1  = __builtin_amdgcn_sinf(th1);
        const float c1  = __builtin_amdgcn_cosf(th1);

        const float kr0 = e0 * c0, ki0 = e0 * s0;
        const float kr1 = e1 * c1, ki1 = e1 * s1;
        const float Pr0 = fmaf(qa0.z, kr0, -qa0.w * ki0);
        const float Pi0 = fmaf(qa0.z, ki0,  qa0.w * kr0);
        const float Pr1 = fmaf(qa1.z, kr1, -qa1.w * ki1);
        const float Pi1 = fmaf(qa1.z, ki1,  qa1.w * kr1);

        v2f y0 = (v2f){Pr0, Pr1};
        v2f y1 = (v2f){fmaf(Pr0, qb0.x, -Pi0 * qb0.y),
                       fmaf(Pr1, qb1.x, -Pi1 * qb1.y)};
        const v2f a2 = (v2f){qb0.z, qb1.z};   // 2*Re(S)
        const v2f nb = (v2f){qb0.w, qb1.w};   // |S|^2

        acc2[0] += y0;
        acc2[1] += y1;
#pragma unroll
        for (int j = 2; j < T_PER_THREAD; ++j) {
            const v2f t = nb * y0;                               // v_pk_mul_f32
            const v2f y = __builtin_elementwise_fma(a2, y1, -t); // v_pk_fma_f32
            acc2[j] += y;                                        // v_pk_add_f32
            y0 = y1;
            y1 = y;
        }

        qa0 = ra0; qb0 = rb0; qa1 = ra1; qb1 = rb1;
    }

    const size_t base = (size_t)h * (size_t)L + (size_t)l0;
    if (l0 + T_PER_THREAD <= L) {
#pragma unroll
        for (int k = 0; k < T_PER_THREAD / 4; ++k) {
            *reinterpret_cast<float4*>(&out[base + 4 * k]) = make_float4(
                acc2[4 * k + 0].x + acc2[4 * k + 0].y,
                acc2[4 * k + 1].x + acc2[4 * k + 1].y,
                acc2[4 * k + 2].x + acc2[4 * k + 2].y,
                acc2[4 * k + 3].x + acc2[4 * k + 3].y);
        }
    } else {
        for (int j = 0; j < T_PER_THREAD && l0 + j < L; ++j)
            out[base + j] = acc2[j].x + acc2[j].y;
    }
}

extern "C" void kernel_launch(void* const* d_in, const int* in_sizes, int n_in,
                              void* d_out, int out_size, void* d_ws, size_t ws_size,
                              hipStream_t stream)
{
    const float* log_dt     = (const float*)d_in[0];
    const float* C          = (const float*)d_in[1];
    const float* log_A_real = (const float*)d_in[2];
    const float* A_imag     = (const float*)d_in[3];
    float* out = (float*)d_out;

    const int H  = in_sizes[0];               // log_dt is (H,)
    const int Nh = in_sizes[2] / H;           // log_A_real is (H, Nh), Nh even
    const int L  = out_size / H;              // out is (H, L)

    const int lPerBlock  = 256 * T_PER_THREAD;            // 4096
    const int blocksPerH = (L + lPerBlock - 1) / lPerBlock;
    const int grid       = H * blocksPerH;
    const size_t smem    = 2 * (size_t)Nh * sizeof(float4);

    hipLaunchKernelGGL(s4d_goertzel2, dim3(grid), dim3(256), smem, stream,
                       log_dt, C, log_A_real, A_imag, out,
                       Nh, L, blocksPerH);
}